// Round 7
// baseline (339.047 us; speedup 1.0000x reference)
//
#include <hip/hip_runtime.h>
#include <stdint.h>

// DILATE loss, B=32, L=512, DIM=16, gamma=1e-3, alpha=0.5.
//
// Round-7 structure (ATTRIBUTION SPLIT: fwd and trace as separate kernels so
// rocprof tells us which phase's cost model is broken):
//   kA : D[b][j][i] column-major.
//   kF : skew-2 forward hard-min DP (one wave per batch); dir tiles
//        (u64 = 8 rows x 4 cols, 2 planes: bit16*1+? see below) stored to
//        GLOBAL, one coalesced 8B store per macro-step (fire-and-forget).
//   kT : per-batch: 256 threads bulk-copy the batch's 64KB dir array to LDS,
//        then wave 0 runs the serial path trace, accumulating (i-j)^2.
//   kC : combine -> scalar loss.
//
// Dir encoding (unchanged from round 6, verified absmax 0.0):
//   per (lane,col-pair) u32 w01: bits[15:0]=diag-eq plane, bits[31:16]=up-eq
//   plane; bit for (col parity p, row r) at (p?7:15)-r (plane1 at +16).
//   u64 tile = {lo: col-pair even, hi: col-pair odd}.
//   Decode priority: diag > up > left.

#define N 512
#define NB 32
#define BIGF 1e10f

typedef unsigned int u32;
typedef float f32x4 __attribute__((ext_vector_type(4)));

// ---------------- kA: pairwise squared distances, column-major -------------
__global__ __launch_bounds__(512) void kA(const float* __restrict__ inp,
                                          const float* __restrict__ tgt,
                                          float* __restrict__ Dg) {
    const int b = blockIdx.y;
    const int jc = blockIdx.x;         // group of 4 columns
    const int tid = (int)threadIdx.x;  // row index i0 in [0,512)
    __shared__ float xs[4][16];        // x[j] = inp[b,j]-inp[b,0]
    if (tid < 64) {
        int c = tid >> 4, d = tid & 15;
        int j = jc * 4 + c;
        xs[c][d] = inp[(((size_t)b * N + j) << 4) + d] -
                   inp[(((size_t)b * N) << 4) + d];
    }
    __syncthreads();
    const float4* t4 = (const float4*)(tgt + (((size_t)b * N + tid) << 4));
    float4 ta = t4[0], tb = t4[1], tc = t4[2], td = t4[3];
    float* out = Dg + ((size_t)b * N + (size_t)jc * 4) * N + tid;
#pragma unroll
    for (int c = 0; c < 4; ++c) {
        float s = 0.f, e;
        e = ta.x - xs[c][0];  s = fmaf(e, e, s);
        e = ta.y - xs[c][1];  s = fmaf(e, e, s);
        e = ta.z - xs[c][2];  s = fmaf(e, e, s);
        e = ta.w - xs[c][3];  s = fmaf(e, e, s);
        e = tb.x - xs[c][4];  s = fmaf(e, e, s);
        e = tb.y - xs[c][5];  s = fmaf(e, e, s);
        e = tb.z - xs[c][6];  s = fmaf(e, e, s);
        e = tb.w - xs[c][7];  s = fmaf(e, e, s);
        e = tc.x - xs[c][8];  s = fmaf(e, e, s);
        e = tc.y - xs[c][9];  s = fmaf(e, e, s);
        e = tc.z - xs[c][10]; s = fmaf(e, e, s);
        e = tc.w - xs[c][11]; s = fmaf(e, e, s);
        e = td.x - xs[c][12]; s = fmaf(e, e, s);
        e = td.y - xs[c][13]; s = fmaf(e, e, s);
        e = td.z - xs[c][14]; s = fmaf(e, e, s);
        e = td.w - xs[c][15]; s = fmaf(e, e, s);
        out[(size_t)c * N] = s;
    }
}

// ---------------- kF: forward DP (skew-2), dirs to global ------------------
#define DIRQ (129 * 64)  // per-batch dir words (quad 0..127 real, 128 dump)

__global__ __launch_bounds__(64) void kF(const float* __restrict__ Dg,
                                         uint2* __restrict__ dirG,
                                         float* __restrict__ acc) {
    const int b = blockIdx.x;
    const int l = (int)threadIdx.x;
    const float* Db = Dg + (size_t)b * N * N;
    uint2* __restrict__ dirB = dirG + (size_t)b * DIRQ;

    // slot data: columns cA (A0:rows0-3, A1:rows4-7) and cB (B0,B1)
    f32x4 A0[4], A1[4], B0[4], B1[4];
    const float* pS[4];

#define LOADC(s_, Tt)                                                         \
    do {                                                                      \
        int c_ = min(max(2 * ((Tt) - l), 0), 510);                            \
        const float* p_ = Db + ((size_t)c_ << 9) + (l << 3);                  \
        A0[s_] = ((const f32x4*)p_)[0];  A1[s_] = ((const f32x4*)p_)[1];      \
        B0[s_] = ((const f32x4*)(p_ + 512))[0];                               \
        B1[s_] = ((const f32x4*)(p_ + 512))[1];                               \
    } while (0)

#define LOADP(s_)                                                             \
    do {                                                                      \
        A0[s_] = ((const f32x4*)pS[s_])[0];                                   \
        A1[s_] = ((const f32x4*)pS[s_])[1];                                   \
        B0[s_] = ((const f32x4*)(pS[s_] + 512))[0];                           \
        B1[s_] = ((const f32x4*)(pS[s_] + 512))[1];                           \
        pS[s_] += 4096;                                                       \
    } while (0)

    float Rprev[8];
#pragma unroll
    for (int r = 0; r < 8; ++r) Rprev[r] = BIGF;
    float sA = BIGF, sB = BIGF, sBold = BIGF, Rfin = 0.f;
    u32 q0 = 0, q1 = 0;

    LOADC(0, 0); LOADC(1, 1); LOADC(2, 2); LOADC(3, 3);

    // PH: 0=prologue (validity+clamped reload), 1=steady, 2=epilogue
#define MSTEP(T_, s_, PH)                                                     \
    do {                                                                      \
        const int cpair = (T_) - l;                                           \
        const bool valid = (PH == 1) || ((unsigned)cpair < 256u);             \
        float dA0 = (l == 0) ? BIGF : sBold;                                  \
        if (PH == 0) dA0 = (l == 0 && (T_) == 0) ? 0.f : dA0;                 \
        const float upA0 = (l == 0) ? BIGF : sA;                              \
        const float upB0 = (l == 0) ? BIGF : sB;                              \
        float RcA[8], RcB[8];                                                 \
        u32 w0 = 0, w1 = 0;                                                   \
        _Pragma("unroll") for (int r = 0; r < 8; ++r) {                       \
            float up = (r == 0) ? upA0 : RcA[r - 1];                          \
            float dg = (r == 0) ? dA0 : Rprev[r - 1];                         \
            float lf = Rprev[r];                                              \
            float mn = fminf(up, fminf(dg, lf));                              \
            w0 = w0 + w0 + (u32)(mn == dg);                                   \
            w1 = w1 + w1 + (u32)(mn == up);                                   \
            RcA[r] = ((r < 4) ? A0[s_][(r) & 3] : A1[s_][(r) & 3]) + mn;      \
        }                                                                     \
        _Pragma("unroll") for (int r = 0; r < 8; ++r) {                       \
            float up = (r == 0) ? upB0 : RcB[r - 1];                          \
            float dg = (r == 0) ? upA0 : RcA[r - 1];                          \
            float lf = RcA[r];                                                \
            float mn = fminf(up, fminf(dg, lf));                              \
            w0 = w0 + w0 + (u32)(mn == dg);                                   \
            w1 = w1 + w1 + (u32)(mn == up);                                   \
            RcB[r] = ((r < 4) ? B0[s_][(r) & 3] : B1[s_][(r) & 3]) + mn;      \
        }                                                                     \
        if (PH == 1) {                                                        \
            _Pragma("unroll") for (int r = 0; r < 8; ++r) Rprev[r] = RcB[r];  \
        } else {                                                              \
            _Pragma("unroll") for (int r = 0; r < 8; ++r)                     \
                Rprev[r] = valid ? RcB[r] : Rprev[r];                         \
        }                                                                     \
        const u32 w01 = (w1 << 16) | w0;                                      \
        const int h = cpair & 1;                                              \
        q0 = h ? q0 : w01;                                                    \
        q1 = h ? w01 : q1;                                                    \
        const int quad = (PH == 1) ? (cpair >> 1) : (valid ? (cpair >> 1) : 128); \
        dirB[(quad << 6) | l] = make_uint2(q0, q1);                           \
        float exA = RcA[7], exB = RcB[7];                                     \
        if (PH != 1) {                                                        \
            exA = valid ? exA : BIGF;                                         \
            exB = valid ? exB : BIGF;                                         \
        }                                                                     \
        if (PH == 2) { if (cpair == 255) Rfin = RcB[7]; }                     \
        sBold = sB;                                                           \
        sA = __shfl_up(exA, 1);                                               \
        sB = __shfl_up(exB, 1);                                               \
        if (PH == 1) { LOADP(s_); } else { LOADC(s_, (T_) + 4); }             \
    } while (0)

    // prologue: T = 0..63
    for (int T = 0; T < 64; T += 4) {
        MSTEP(T + 0, 0, 0); MSTEP(T + 1, 1, 0);
        MSTEP(T + 2, 2, 0); MSTEP(T + 3, 3, 0);
    }
    // steady: T = 64..251 (all lanes valid; reload targets T+4 <= 255 valid)
#pragma unroll
    for (int s = 0; s < 4; ++s)
        pS[s] = Db + ((size_t)(2 * (68 + s - l)) << 9) + (l << 3);
    for (int T = 64; T < 252; T += 4) {
        MSTEP(T + 0, 0, 1); MSTEP(T + 1, 1, 1);
        MSTEP(T + 2, 2, 1); MSTEP(T + 3, 3, 1);
    }
    // epilogue: T = 252..319 (covers last real step T=318; T=319 all-dump)
    for (int T = 252; T < 320; T += 4) {
        MSTEP(T + 0, 0, 2); MSTEP(T + 1, 1, 2);
        MSTEP(T + 2, 2, 2); MSTEP(T + 3, 3, 2);
    }
#undef MSTEP
#undef LOADC
#undef LOADP

    if (l == 63) acc[b] = Rfin;  // Rp[N,N]: hard-DTW value
}

// ---------------- kT: path trace from bulk-loaded LDS ----------------------
__global__ __launch_bounds__(256) void kT(const uint2* __restrict__ dirG,
                                          float* __restrict__ acc) {
    const int b = blockIdx.x;
    const int tid = (int)threadIdx.x;
    __shared__ uint2 tile[128 * 64];  // 64 KB

    // bulk copy: 4096 uint4 = 64KB, 16 fully-coalesced iters of 256 threads
    const uint4* src = (const uint4*)(dirG + (size_t)b * DIRQ);
    uint4* dst = (uint4*)tile;
#pragma unroll
    for (int it = 0; it < 16; ++it) dst[it * 256 + tid] = src[it * 256 + tid];
    __syncthreads();

    if (tid < 64) {
        int i = N, j = N;  // 1-based
        float tsum = 0.f;
        int L = (N - 1) >> 3, Q = (N - 1) >> 2;  // 63, 127
        uint2 w = tile[(Q << 6) | L];
        bool done = false;
        for (int g = 0; g < 1100 && !done; ++g) {
            const int Lm = L > 0 ? L - 1 : 0;
            const int Qm = Q > 0 ? Q - 1 : 0;
            uint2 wU = tile[(Q << 6) | Lm];   // cross row-block, same quad
            uint2 wL = tile[(Qm << 6) | L];   // same row-block, quad left
            uint2 wD = tile[(Qm << 6) | Lm];  // both
            while (true) {
                const int row0 = i - 1, col0 = j - 1;
                const u32 v = ((col0 >> 1) & 1) ? w.y : w.x;
                const int s = ((col0 & 1) ? 7 : 15) - (row0 & 7);
                const u32 bd = (v >> s) & 1u;
                const u32 bu = (v >> (s + 16)) & 1u;
                const int di = (int)(bd | bu);
                const int dj = (int)(bd | (bu ^ 1u));  // diag/left move j
                i -= di; j -= dj;
                const int d = i - j;
                tsum += (float)(d * d);
                if ((i | j) == 1) { done = true; break; }  // reached (1,1)
                const int nL = (i - 1) >> 3, nQ = (j - 1) >> 2;
                if ((nL != L) || (nQ != Q)) {
                    w = (nQ != Q) ? ((nL != L) ? wD : wL) : wU;
                    L = nL; Q = nQ;
                    break;  // re-speculate neighbors
                }
            }
        }
        if (tid == 0) acc[NB + b] = tsum;
    }
}

// ---------------- kC: combine over batches ---------------------------------
__global__ void kC(const float* __restrict__ acc, float* __restrict__ out) {
    const int l = (int)threadIdx.x;
    float vs = (l < NB) ? acc[l] : 0.f;
    float vt = (l < NB) ? acc[NB + l] : 0.f;
#pragma unroll
    for (int o = 32; o >= 1; o >>= 1) {
        vs += __shfl_down(vs, o);
        vt += __shfl_down(vt, o);
    }
    if (l == 0)
        out[0] = 0.5f * (vs / (float)NB) +
                 0.5f * (vt / ((float)NB * (float)(N * N)));
}

__global__ void kSentinel(float* out) { out[0] = -12345.0f; }

extern "C" void kernel_launch(void* const* d_in, const int* in_sizes, int n_in,
                              void* d_out, int out_size, void* d_ws, size_t ws_size,
                              hipStream_t stream) {
    const float* inp = (const float*)d_in[0];
    const float* tgt = (const float*)d_in[1];
    float* out = (float*)d_out;

    const size_t DSZ = (size_t)NB * N * N * sizeof(float);   // 32 MiB
    const size_t DIRSZ = (size_t)NB * DIRQ * sizeof(uint2);  // ~2 MiB
    const size_t NEEDED = 256 + DSZ + DIRSZ;
    if (ws_size < NEEDED) {
        kSentinel<<<1, 1, 0, stream>>>(out);
        return;
    }
    char* ws = (char*)d_ws;
    float* acc = (float*)ws;  // [0..31] shape, [32..63] temporal
    float* Dg = (float*)(ws + 256);
    uint2* dirG = (uint2*)(ws + 256 + DSZ);

    kA<<<dim3(N / 4, NB), 512, 0, stream>>>(inp, tgt, Dg);
    kF<<<NB, 64, 0, stream>>>(Dg, dirG, acc);
    kT<<<NB, 256, 0, stream>>>(dirG, acc);
    kC<<<1, 64, 0, stream>>>(acc, out);
}

// Round 8
// 123.523 us; speedup vs baseline: 2.7448x; 2.7448x over previous
//
#include <hip/hip_runtime.h>
#include <stdint.h>

// DILATE loss, B=32, L=512, DIM=16, gamma=1e-3, alpha=0.5.
//
// Round-8 structure:
//   kA : D[b][j][i] column-major.
//   kFT: one wave per batch, skew-2 forward hard-min DP carrying BOTH
//        R (soft-DTW value, gamma->0) and T (= sum of (i-j)^2 along the
//        argmin path) through the same wavefront:
//          T[i,j] = T[argmin parent] + (i-j)^2
//        selected with the same compares as R (priority diag > up > left).
//        No dir codes, no LDS, no trace kernel (round 7 showed the serial
//        trace cost 200us = ~470 cyc/cell; this replaces it with ~6
//        issue-bound VALU ops/cell inside the existing DP).
//   kC : combine -> scalar loss.

#define N 512
#define NB 32
#define BIGF 1e10f

typedef unsigned int u32;
typedef float f32x4 __attribute__((ext_vector_type(4)));

// ---------------- kA: pairwise squared distances, column-major -------------
__global__ __launch_bounds__(512) void kA(const float* __restrict__ inp,
                                          const float* __restrict__ tgt,
                                          float* __restrict__ Dg) {
    const int b = blockIdx.y;
    const int jc = blockIdx.x;         // group of 4 columns
    const int tid = (int)threadIdx.x;  // row index i0 in [0,512)
    __shared__ float xs[4][16];        // x[j] = inp[b,j]-inp[b,0]
    if (tid < 64) {
        int c = tid >> 4, d = tid & 15;
        int j = jc * 4 + c;
        xs[c][d] = inp[(((size_t)b * N + j) << 4) + d] -
                   inp[(((size_t)b * N) << 4) + d];
    }
    __syncthreads();
    const float4* t4 = (const float4*)(tgt + (((size_t)b * N + tid) << 4));
    float4 ta = t4[0], tb = t4[1], tc = t4[2], td = t4[3];
    float* out = Dg + ((size_t)b * N + (size_t)jc * 4) * N + tid;
#pragma unroll
    for (int c = 0; c < 4; ++c) {
        float s = 0.f, e;
        e = ta.x - xs[c][0];  s = fmaf(e, e, s);
        e = ta.y - xs[c][1];  s = fmaf(e, e, s);
        e = ta.z - xs[c][2];  s = fmaf(e, e, s);
        e = ta.w - xs[c][3];  s = fmaf(e, e, s);
        e = tb.x - xs[c][4];  s = fmaf(e, e, s);
        e = tb.y - xs[c][5];  s = fmaf(e, e, s);
        e = tb.z - xs[c][6];  s = fmaf(e, e, s);
        e = tb.w - xs[c][7];  s = fmaf(e, e, s);
        e = tc.x - xs[c][8];  s = fmaf(e, e, s);
        e = tc.y - xs[c][9];  s = fmaf(e, e, s);
        e = tc.z - xs[c][10]; s = fmaf(e, e, s);
        e = tc.w - xs[c][11]; s = fmaf(e, e, s);
        e = td.x - xs[c][12]; s = fmaf(e, e, s);
        e = td.y - xs[c][13]; s = fmaf(e, e, s);
        e = td.z - xs[c][14]; s = fmaf(e, e, s);
        e = td.w - xs[c][15]; s = fmaf(e, e, s);
        out[(size_t)c * N] = s;
    }
}

// ---------------- kFT: forward DP (skew-2) with in-DP path sum -------------
__global__ __launch_bounds__(64) void kFT(const float* __restrict__ Dg,
                                          float* __restrict__ acc) {
    const int b = blockIdx.x;
    const int l = (int)threadIdx.x;
    const float* Db = Dg + (size_t)b * N * N;

    // slot data: columns cA (A0:rows0-3, A1:rows4-7) and cB (B0,B1)
    f32x4 A0[4], A1[4], B0[4], B1[4];
    const float* pS[4];

#define LOADC(s_, Tt)                                                         \
    do {                                                                      \
        int c_ = min(max(2 * ((Tt) - l), 0), 510);                            \
        const float* p_ = Db + ((size_t)c_ << 9) + (l << 3);                  \
        A0[s_] = ((const f32x4*)p_)[0];  A1[s_] = ((const f32x4*)p_)[1];      \
        B0[s_] = ((const f32x4*)(p_ + 512))[0];                               \
        B1[s_] = ((const f32x4*)(p_ + 512))[1];                               \
    } while (0)

#define LOADP(s_)                                                             \
    do {                                                                      \
        A0[s_] = ((const f32x4*)pS[s_])[0];                                   \
        A1[s_] = ((const f32x4*)pS[s_])[1];                                   \
        B0[s_] = ((const f32x4*)(pS[s_] + 512))[0];                           \
        B1[s_] = ((const f32x4*)(pS[s_] + 512))[1];                           \
        pS[s_] += 4096;                                                       \
    } while (0)

    float Rprev[8], Tprev[8];
#pragma unroll
    for (int r = 0; r < 8; ++r) { Rprev[r] = BIGF; Tprev[r] = 0.f; }
    float sA = BIGF, sB = BIGF, sBold = BIGF;
    float tA = 0.f, tB = 0.f, tBold = 0.f;
    float Rfin = 0.f, Tfin = 0.f;
    // d = i - j for (row 8l+1+r, col-pair cpair): base (r=0, col A) is
    // 8l - 2*cpair... maintained incrementally: dbA = 10l - 2T, -=2 per step.
    float dbA = (float)(10 * l);

    LOADC(0, 0); LOADC(1, 1); LOADC(2, 2); LOADC(3, 3);

    // PH: 0=prologue (validity+clamped reload), 1=steady, 2=epilogue
#define MSTEP(T_, s_, PH)                                                     \
    do {                                                                      \
        const int cpair = (T_) - l;                                           \
        const bool valid = (PH == 1) || ((unsigned)cpair < 256u);             \
        float dA0 = (l == 0) ? BIGF : sBold;                                  \
        if (PH == 0) dA0 = (l == 0 && (T_) == 0) ? 0.f : dA0;                 \
        const float upA0 = (l == 0) ? BIGF : sA;                              \
        const float upB0 = (l == 0) ? BIGF : sB;                              \
        const float dA0T = (l == 0) ? 0.f : tBold;                            \
        const float upA0T = (l == 0) ? 0.f : tA;                              \
        const float upB0T = (l == 0) ? 0.f : tB;                              \
        const float dbB = dbA - 1.0f;                                         \
        float RcA[8], RcB[8], TcA[8], TcB[8];                                 \
        _Pragma("unroll") for (int r = 0; r < 8; ++r) {                       \
            float up = (r == 0) ? upA0 : RcA[r - 1];                          \
            float dg = (r == 0) ? dA0 : Rprev[r - 1];                         \
            float lf = Rprev[r];                                              \
            float upT = (r == 0) ? upA0T : TcA[r - 1];                        \
            float dgT = (r == 0) ? dA0T : Tprev[r - 1];                       \
            float lfT = Tprev[r];                                             \
            float mn = fminf(up, fminf(dg, lf));                              \
            float Ts = (mn == dg) ? dgT : ((mn == up) ? upT : lfT);           \
            float dr = dbA + (float)r;                                        \
            TcA[r] = fmaf(dr, dr, Ts);                                        \
            RcA[r] = ((r < 4) ? A0[s_][(r) & 3] : A1[s_][(r) & 3]) + mn;      \
        }                                                                     \
        _Pragma("unroll") for (int r = 0; r < 8; ++r) {                       \
            float up = (r == 0) ? upB0 : RcB[r - 1];                          \
            float dg = (r == 0) ? upA0 : RcA[r - 1];                          \
            float lf = RcA[r];                                                \
            float upT = (r == 0) ? upB0T : TcB[r - 1];                        \
            float dgT = (r == 0) ? upA0T : TcA[r - 1];                        \
            float lfT = TcA[r];                                               \
            float mn = fminf(up, fminf(dg, lf));                              \
            float Ts = (mn == dg) ? dgT : ((mn == up) ? upT : lfT);           \
            float dr = dbB + (float)r;                                        \
            TcB[r] = fmaf(dr, dr, Ts);                                        \
            RcB[r] = ((r < 4) ? B0[s_][(r) & 3] : B1[s_][(r) & 3]) + mn;      \
        }                                                                     \
        if (PH == 1) {                                                        \
            _Pragma("unroll") for (int r = 0; r < 8; ++r) {                   \
                Rprev[r] = RcB[r]; Tprev[r] = TcB[r];                         \
            }                                                                 \
        } else {                                                              \
            _Pragma("unroll") for (int r = 0; r < 8; ++r) {                   \
                Rprev[r] = valid ? RcB[r] : Rprev[r];                         \
                Tprev[r] = valid ? TcB[r] : Tprev[r];                         \
            }                                                                 \
        }                                                                     \
        float exA = RcA[7], exB = RcB[7], exAT = TcA[7], exBT = TcB[7];       \
        if (PH != 1) {                                                        \
            exA = valid ? exA : BIGF;                                         \
            exB = valid ? exB : BIGF;                                         \
            exAT = valid ? exAT : 0.f;                                        \
            exBT = valid ? exBT : 0.f;                                        \
        }                                                                     \
        if (PH == 2) {                                                        \
            if (cpair == 255) { Rfin = RcB[7]; Tfin = TcB[7]; }               \
        }                                                                     \
        sBold = sB; tBold = tB;                                               \
        sA = __shfl_up(exA, 1);                                               \
        sB = __shfl_up(exB, 1);                                               \
        tA = __shfl_up(exAT, 1);                                              \
        tB = __shfl_up(exBT, 1);                                              \
        dbA -= 2.0f;                                                          \
        if (PH == 1) { LOADP(s_); } else { LOADC(s_, (T_) + 4); }             \
    } while (0)

    // prologue: T = 0..63
    for (int T = 0; T < 64; T += 4) {
        MSTEP(T + 0, 0, 0); MSTEP(T + 1, 1, 0);
        MSTEP(T + 2, 2, 0); MSTEP(T + 3, 3, 0);
    }
    // steady: T = 64..251 (all lanes valid; reloads target cols <= 510)
#pragma unroll
    for (int s = 0; s < 4; ++s)
        pS[s] = Db + ((size_t)(2 * (68 + s - l)) << 9) + (l << 3);
    for (int T = 64; T < 252; T += 4) {
        MSTEP(T + 0, 0, 1); MSTEP(T + 1, 1, 1);
        MSTEP(T + 2, 2, 1); MSTEP(T + 3, 3, 1);
    }
    // epilogue: T = 252..319 (covers last real step T=318; T=319 all-dump)
    for (int T = 252; T < 320; T += 4) {
        MSTEP(T + 0, 0, 2); MSTEP(T + 1, 1, 2);
        MSTEP(T + 2, 2, 2); MSTEP(T + 3, 3, 2);
    }
#undef MSTEP
#undef LOADC
#undef LOADP

    if (l == 63) {
        acc[b] = Rfin;       // Rp[N,N]: hard-DTW value
        acc[NB + b] = Tfin;  // sum (i-j)^2 along argmin path
    }
}

// ---------------- kC: combine over batches ---------------------------------
__global__ void kC(const float* __restrict__ acc, float* __restrict__ out) {
    const int l = (int)threadIdx.x;
    float vs = (l < NB) ? acc[l] : 0.f;
    float vt = (l < NB) ? acc[NB + l] : 0.f;
#pragma unroll
    for (int o = 32; o >= 1; o >>= 1) {
        vs += __shfl_down(vs, o);
        vt += __shfl_down(vt, o);
    }
    if (l == 0)
        out[0] = 0.5f * (vs / (float)NB) +
                 0.5f * (vt / ((float)NB * (float)(N * N)));
}

__global__ void kSentinel(float* out) { out[0] = -12345.0f; }

extern "C" void kernel_launch(void* const* d_in, const int* in_sizes, int n_in,
                              void* d_out, int out_size, void* d_ws, size_t ws_size,
                              hipStream_t stream) {
    const float* inp = (const float*)d_in[0];
    const float* tgt = (const float*)d_in[1];
    float* out = (float*)d_out;

    const size_t DSZ = (size_t)NB * N * N * sizeof(float);  // 32 MiB
    const size_t NEEDED = 256 + DSZ;
    if (ws_size < NEEDED) {
        kSentinel<<<1, 1, 0, stream>>>(out);
        return;
    }
    char* ws = (char*)d_ws;
    float* acc = (float*)ws;  // [0..31] shape, [32..63] temporal
    float* Dg = (float*)(ws + 256);

    kA<<<dim3(N / 4, NB), 512, 0, stream>>>(inp, tgt, Dg);
    kFT<<<NB, 64, 0, stream>>>(Dg, acc);
    kC<<<1, 64, 0, stream>>>(acc, out);
}